// Round 1
// baseline (1263.051 us; speedup 1.0000x reference)
//
#include <hip/hip_runtime.h>

// hnode_prompt_layer_feature_cat_edge
// out[dst, 0:128]   += emb[src] * w        (segment sum over edges)
// out[dst, 128:160] += e_feat[e]
//
// Edge-parallel atomic scatter. 32 threads per edge for the 128-wide ft part
// (float4 per thread), 8 threads per edge for the 32-wide edge-feature part.

#define D_FT 128
#define D_E 32
#define D_OUT (D_FT + D_E)

__global__ void scatter_ft_kernel(const float* __restrict__ emb,
                                  const float* __restrict__ w,
                                  const int* __restrict__ src_idx,
                                  const int* __restrict__ dst_idx,
                                  float* __restrict__ out,
                                  int n_items) {
    int idx = blockIdx.x * blockDim.x + threadIdx.x;
    if (idx >= n_items) return;
    int e = idx >> 5;        // edge
    int q = idx & 31;        // float4 slot within the 128-wide row
    int s = src_idx[e];
    int d = dst_idx[e];
    const float4 v  = *reinterpret_cast<const float4*>(emb + (size_t)s * D_FT + q * 4);
    const float4 wv = *reinterpret_cast<const float4*>(w + q * 4);
    float* o = out + (size_t)d * D_OUT + q * 4;
    atomicAdd(o + 0, v.x * wv.x);
    atomicAdd(o + 1, v.y * wv.y);
    atomicAdd(o + 2, v.z * wv.z);
    atomicAdd(o + 3, v.w * wv.w);
}

__global__ void scatter_e_kernel(const float* __restrict__ e_feat,
                                 const int* __restrict__ dst_idx,
                                 float* __restrict__ out,
                                 int n_items) {
    int idx = blockIdx.x * blockDim.x + threadIdx.x;
    if (idx >= n_items) return;
    int e = idx >> 3;        // edge
    int q = idx & 7;         // float4 slot within the 32-wide row
    int d = dst_idx[e];
    const float4 v = *reinterpret_cast<const float4*>(e_feat + (size_t)e * D_E + q * 4);
    float* o = out + (size_t)d * D_OUT + D_FT + q * 4;
    atomicAdd(o + 0, v.x);
    atomicAdd(o + 1, v.y);
    atomicAdd(o + 2, v.z);
    atomicAdd(o + 3, v.w);
}

extern "C" void kernel_launch(void* const* d_in, const int* in_sizes, int n_in,
                              void* d_out, int out_size, void* d_ws, size_t ws_size,
                              hipStream_t stream) {
    const float* emb    = (const float*)d_in[0];   // [N, 128]
    const float* e_feat = (const float*)d_in[1];   // [E, 32]
    const float* w      = (const float*)d_in[2];   // [1, 128]
    const int*   src    = (const int*)d_in[3];     // [E]
    const int*   dst    = (const int*)d_in[4];     // [E]
    float* out = (float*)d_out;                    // [N, 160]

    const int E = in_sizes[3];

    // Output accumulates via atomics: must zero every call (harness does not
    // re-zero between graph replays).
    hipMemsetAsync(d_out, 0, (size_t)out_size * sizeof(float), stream);

    int items_ft = E * 32;   // one float4 per item
    int items_e  = E * 8;
    scatter_ft_kernel<<<(items_ft + 255) / 256, 256, 0, stream>>>(emb, w, src, dst, out, items_ft);
    scatter_e_kernel<<<(items_e + 255) / 256, 256, 0, stream>>>(e_feat, dst, out, items_e);
}

// Round 2
// 224.050 us; speedup vs baseline: 5.6374x; 5.6374x over previous
//
#include <hip/hip_runtime.h>

// hnode_prompt_layer_feature_cat_edge
// out[d, 0:128]   = (sum_{e: dst[e]=d} emb[src[e]]) * w
// out[d, 128:160] =  sum_{e: dst[e]=d} e_feat[e]
//
// Strategy: build by-destination CSR each call (hist -> scan -> place),
// then pull-gather: 32 threads/node accumulate in registers, write once.
// Eliminates the 76.8M fp32 atomics (1.2 GB HBM write amplification in R1).

#define D_FT 128
#define D_E 32
#define D_OUT (D_FT + D_E)

__global__ void hist_kernel(const int* __restrict__ dst, int* __restrict__ counts, int E) {
    int i = blockIdx.x * blockDim.x + threadIdx.x;
    if (i < E) atomicAdd(&counts[dst[i]], 1);
}

// Single-block exclusive scan over N counts -> offsets[0..N], cursor = copy.
__global__ void scan_kernel(const int* __restrict__ counts, int* __restrict__ offsets,
                            int* __restrict__ cursor, int N) {
    __shared__ int lds[1024];
    __shared__ int carry;
    const int tid = threadIdx.x;
    if (tid == 0) carry = 0;
    __syncthreads();
    for (int base = 0; base < N; base += 1024) {
        int i = base + tid;
        int x = (i < N) ? counts[i] : 0;
        int v = x;
        lds[tid] = v;
        __syncthreads();
        for (int off = 1; off < 1024; off <<= 1) {
            int add = (tid >= off) ? lds[tid - off] : 0;
            __syncthreads();
            v += add;
            lds[tid] = v;
            __syncthreads();
        }
        int excl = v - x + carry;   // exclusive prefix + chunk carry
        if (i < N) { offsets[i] = excl; cursor[i] = excl; }
        __syncthreads();
        if (tid == 1023) carry += lds[1023];  // chunk total
        __syncthreads();
    }
    if (tid == 0) offsets[N] = carry;
}

__global__ void place_kernel(const int* __restrict__ dst, int* __restrict__ cursor,
                             int* __restrict__ edge_list, int E) {
    int i = blockIdx.x * blockDim.x + threadIdx.x;
    if (i < E) {
        int p = atomicAdd(&cursor[dst[i]], 1);
        edge_list[p] = i;
    }
}

// 32 threads per node: thread q owns ft float4 q (128 cols); threads q<8 also
// own e-feat float4 q (32 cols). Single write per output element.
__global__ void gather_kernel(const float* __restrict__ emb,
                              const float* __restrict__ e_feat,
                              const float* __restrict__ w,
                              const int* __restrict__ src_idx,
                              const int* __restrict__ offsets,
                              const int* __restrict__ edge_list,
                              float* __restrict__ out, int N) {
    int g = (blockIdx.x * blockDim.x + threadIdx.x) >> 5;   // node
    int q = threadIdx.x & 31;
    if (g >= N) return;
    const int beg = offsets[g], end = offsets[g + 1];
    float4 accft = make_float4(0.f, 0.f, 0.f, 0.f);
    float4 acce  = make_float4(0.f, 0.f, 0.f, 0.f);
    for (int e = beg; e < end; ++e) {
        int eid = edge_list[e];
        int s = src_idx[eid];
        float4 v = *reinterpret_cast<const float4*>(emb + (size_t)s * D_FT + q * 4);
        accft.x += v.x; accft.y += v.y; accft.z += v.z; accft.w += v.w;
        if (q < 8) {
            float4 ve = *reinterpret_cast<const float4*>(e_feat + (size_t)eid * D_E + q * 4);
            acce.x += ve.x; acce.y += ve.y; acce.z += ve.z; acce.w += ve.w;
        }
    }
    float4 wv = *reinterpret_cast<const float4*>(w + q * 4);
    float* o = out + (size_t)g * D_OUT;
    *reinterpret_cast<float4*>(o + q * 4) =
        make_float4(accft.x * wv.x, accft.y * wv.y, accft.z * wv.z, accft.w * wv.w);
    if (q < 8)
        *reinterpret_cast<float4*>(o + D_FT + q * 4) = acce;
}

// ---- fallback (R1 atomic path) if ws too small ----
__global__ void scatter_ft_kernel(const float* __restrict__ emb, const float* __restrict__ w,
                                  const int* __restrict__ src_idx, const int* __restrict__ dst_idx,
                                  float* __restrict__ out, int n_items) {
    int idx = blockIdx.x * blockDim.x + threadIdx.x;
    if (idx >= n_items) return;
    int e = idx >> 5, q = idx & 31;
    int s = src_idx[e], d = dst_idx[e];
    const float4 v  = *reinterpret_cast<const float4*>(emb + (size_t)s * D_FT + q * 4);
    const float4 wv = *reinterpret_cast<const float4*>(w + q * 4);
    float* o = out + (size_t)d * D_OUT + q * 4;
    atomicAdd(o + 0, v.x * wv.x); atomicAdd(o + 1, v.y * wv.y);
    atomicAdd(o + 2, v.z * wv.z); atomicAdd(o + 3, v.w * wv.w);
}
__global__ void scatter_e_kernel(const float* __restrict__ e_feat, const int* __restrict__ dst_idx,
                                 float* __restrict__ out, int n_items) {
    int idx = blockIdx.x * blockDim.x + threadIdx.x;
    if (idx >= n_items) return;
    int e = idx >> 3, q = idx & 7;
    int d = dst_idx[e];
    const float4 v = *reinterpret_cast<const float4*>(e_feat + (size_t)e * D_E + q * 4);
    float* o = out + (size_t)d * D_OUT + D_FT + q * 4;
    atomicAdd(o + 0, v.x); atomicAdd(o + 1, v.y);
    atomicAdd(o + 2, v.z); atomicAdd(o + 3, v.w);
}

extern "C" void kernel_launch(void* const* d_in, const int* in_sizes, int n_in,
                              void* d_out, int out_size, void* d_ws, size_t ws_size,
                              hipStream_t stream) {
    const float* emb    = (const float*)d_in[0];   // [N, 128]
    const float* e_feat = (const float*)d_in[1];   // [E, 32]
    const float* w      = (const float*)d_in[2];   // [1, 128]
    const int*   src    = (const int*)d_in[3];     // [E]
    const int*   dst    = (const int*)d_in[4];     // [E]
    float* out = (float*)d_out;                    // [N, 160]

    const int E = in_sizes[3];
    const int N = out_size / D_OUT;

    // ws layout (ints): counts[N] | offsets[N+1] | cursor[N] | edge_list[E]
    size_t need = ((size_t)N * 3 + 1 + (size_t)E) * sizeof(int);
    if (ws_size >= need) {
        int* counts    = (int*)d_ws;
        int* offsets   = counts + N;
        int* cursor    = offsets + N + 1;
        int* edge_list = cursor + N;

        hipMemsetAsync(counts, 0, (size_t)N * sizeof(int), stream);
        hist_kernel<<<(E + 255) / 256, 256, 0, stream>>>(dst, counts, E);
        scan_kernel<<<1, 1024, 0, stream>>>(counts, offsets, cursor, N);
        place_kernel<<<(E + 255) / 256, 256, 0, stream>>>(dst, cursor, edge_list, E);
        int groups = N;  // 32 threads per node, 8 nodes per 256-block
        gather_kernel<<<(groups * 32 + 255) / 256, 256, 0, stream>>>(
            emb, e_feat, w, src, offsets, edge_list, out, N);
    } else {
        hipMemsetAsync(d_out, 0, (size_t)out_size * sizeof(float), stream);
        int items_ft = E * 32, items_e = E * 8;
        scatter_ft_kernel<<<(items_ft + 255) / 256, 256, 0, stream>>>(emb, w, src, dst, out, items_ft);
        scatter_e_kernel<<<(items_e + 255) / 256, 256, 0, stream>>>(e_feat, dst, out, items_e);
    }
}

// Round 3
// 102.835 us; speedup vs baseline: 12.2823x; 2.1787x over previous
//
#include <hip/hip_runtime.h>

// hnode_prompt_layer_feature_cat_edge
// out[d, 0:128]   = (sum_{e: dst[e]=d} emb[src[e]]) * w
// out[d, 128:160] =  sum_{e: dst[e]=d} e_feat[e]
//
// R3: scan-free bucket CSR. place fills bucket[d][0..31] = {src, eid} via
// atomic cursor (overflow -> list, drained by atomic scatter after gather).
// gather: 32 lanes/node, lane q preloads pair q (one 256B coalesced load),
// loop gets indices via __shfl -> emb row loads have no dependent hops.

#define D_FT 128
#define D_E 32
#define D_OUT (D_FT + D_E)
#define CAP 32

__global__ void place_bucket_kernel(const int* __restrict__ src_idx,
                                    const int* __restrict__ dst_idx,
                                    int* __restrict__ cursor,
                                    int2* __restrict__ bucket,
                                    int* __restrict__ ovf,
                                    int* __restrict__ ovf_cnt, int E) {
    int i = blockIdx.x * blockDim.x + threadIdx.x;
    if (i >= E) return;
    int d = dst_idx[i];
    int slot = atomicAdd(&cursor[d], 1);
    if (slot < CAP) {
        int2 pr; pr.x = src_idx[i]; pr.y = i;
        bucket[(size_t)d * CAP + slot] = pr;
    } else {
        int p = atomicAdd(ovf_cnt, 1);
        ovf[p] = i;
    }
}

__global__ void gather_bucket_kernel(const float* __restrict__ emb,
                                     const float* __restrict__ e_feat,
                                     const float* __restrict__ w,
                                     const int* __restrict__ cursor,
                                     const int2* __restrict__ bucket,
                                     float* __restrict__ out, int N) {
    int g = (blockIdx.x * blockDim.x + threadIdx.x) >> 5;   // node
    if (g >= N) return;
    int q = threadIdx.x & 31;
    int cnt = cursor[g];
    cnt = cnt > CAP ? CAP : cnt;
    int2 pr = make_int2(0, 0);
    if (q < cnt) pr = bucket[(size_t)g * CAP + q];

    float4 accft = make_float4(0.f, 0.f, 0.f, 0.f);
    float4 acce  = make_float4(0.f, 0.f, 0.f, 0.f);

    int i = 0;
    for (; i + 2 <= cnt; i += 2) {
        int s0  = __shfl(pr.x, i, 32);
        int e0  = __shfl(pr.y, i, 32);
        int s1  = __shfl(pr.x, i + 1, 32);
        int e1  = __shfl(pr.y, i + 1, 32);
        float4 v0 = *reinterpret_cast<const float4*>(emb + (size_t)s0 * D_FT + q * 4);
        float4 v1 = *reinterpret_cast<const float4*>(emb + (size_t)s1 * D_FT + q * 4);
        accft.x += v0.x + v1.x; accft.y += v0.y + v1.y;
        accft.z += v0.z + v1.z; accft.w += v0.w + v1.w;
        if (q < 8) {
            float4 a0 = *reinterpret_cast<const float4*>(e_feat + (size_t)e0 * D_E + q * 4);
            float4 a1 = *reinterpret_cast<const float4*>(e_feat + (size_t)e1 * D_E + q * 4);
            acce.x += a0.x + a1.x; acce.y += a0.y + a1.y;
            acce.z += a0.z + a1.z; acce.w += a0.w + a1.w;
        }
    }
    if (i < cnt) {
        int s0 = __shfl(pr.x, i, 32);
        int e0 = __shfl(pr.y, i, 32);
        float4 v0 = *reinterpret_cast<const float4*>(emb + (size_t)s0 * D_FT + q * 4);
        accft.x += v0.x; accft.y += v0.y; accft.z += v0.z; accft.w += v0.w;
        if (q < 8) {
            float4 a0 = *reinterpret_cast<const float4*>(e_feat + (size_t)e0 * D_E + q * 4);
            acce.x += a0.x; acce.y += a0.y; acce.z += a0.z; acce.w += a0.w;
        }
    }

    float4 wv = *reinterpret_cast<const float4*>(w + q * 4);
    float* o = out + (size_t)g * D_OUT;
    *reinterpret_cast<float4*>(o + q * 4) =
        make_float4(accft.x * wv.x, accft.y * wv.y, accft.z * wv.z, accft.w * wv.w);
    if (q < 8)
        *reinterpret_cast<float4*>(o + D_FT + q * 4) = acce;
}

// Drain overflow edges (deg > CAP; ~never fires for this data, correct always).
__global__ void ovf_scatter_kernel(const float* __restrict__ emb,
                                   const float* __restrict__ e_feat,
                                   const float* __restrict__ w,
                                   const int* __restrict__ src_idx,
                                   const int* __restrict__ dst_idx,
                                   const int* __restrict__ ovf,
                                   const int* __restrict__ ovf_cnt,
                                   float* __restrict__ out) {
    int n = *ovf_cnt;
    int total = n * 40;   // 32 ft float4-slots + 8 e float4-slots per edge
    for (int t = blockIdx.x * blockDim.x + threadIdx.x; t < total;
         t += gridDim.x * blockDim.x) {
        int e = t / 40, slot = t % 40;
        int eid = ovf[e];
        int d = dst_idx[eid];
        float* o = out + (size_t)d * D_OUT;
        if (slot < 32) {
            int s = src_idx[eid];
            float4 v  = *reinterpret_cast<const float4*>(emb + (size_t)s * D_FT + slot * 4);
            float4 wv = *reinterpret_cast<const float4*>(w + slot * 4);
            atomicAdd(o + slot * 4 + 0, v.x * wv.x);
            atomicAdd(o + slot * 4 + 1, v.y * wv.y);
            atomicAdd(o + slot * 4 + 2, v.z * wv.z);
            atomicAdd(o + slot * 4 + 3, v.w * wv.w);
        } else {
            int q = slot - 32;
            float4 ve = *reinterpret_cast<const float4*>(e_feat + (size_t)eid * D_E + q * 4);
            atomicAdd(o + D_FT + q * 4 + 0, ve.x);
            atomicAdd(o + D_FT + q * 4 + 1, ve.y);
            atomicAdd(o + D_FT + q * 4 + 2, ve.z);
            atomicAdd(o + D_FT + q * 4 + 3, ve.w);
        }
    }
}

// ---- fallback (R1 atomic path) if ws too small ----
__global__ void scatter_ft_kernel(const float* __restrict__ emb, const float* __restrict__ w,
                                  const int* __restrict__ src_idx, const int* __restrict__ dst_idx,
                                  float* __restrict__ out, int n_items) {
    int idx = blockIdx.x * blockDim.x + threadIdx.x;
    if (idx >= n_items) return;
    int e = idx >> 5, q = idx & 31;
    int s = src_idx[e], d = dst_idx[e];
    const float4 v  = *reinterpret_cast<const float4*>(emb + (size_t)s * D_FT + q * 4);
    const float4 wv = *reinterpret_cast<const float4*>(w + q * 4);
    float* o = out + (size_t)d * D_OUT + q * 4;
    atomicAdd(o + 0, v.x * wv.x); atomicAdd(o + 1, v.y * wv.y);
    atomicAdd(o + 2, v.z * wv.z); atomicAdd(o + 3, v.w * wv.w);
}
__global__ void scatter_e_kernel(const float* __restrict__ e_feat, const int* __restrict__ dst_idx,
                                 float* __restrict__ out, int n_items) {
    int idx = blockIdx.x * blockDim.x + threadIdx.x;
    if (idx >= n_items) return;
    int e = idx >> 3, q = idx & 7;
    int d = dst_idx[e];
    const float4 v = *reinterpret_cast<const float4*>(e_feat + (size_t)e * D_E + q * 4);
    float* o = out + (size_t)d * D_OUT + D_FT + q * 4;
    atomicAdd(o + 0, v.x); atomicAdd(o + 1, v.y);
    atomicAdd(o + 2, v.z); atomicAdd(o + 3, v.w);
}

extern "C" void kernel_launch(void* const* d_in, const int* in_sizes, int n_in,
                              void* d_out, int out_size, void* d_ws, size_t ws_size,
                              hipStream_t stream) {
    const float* emb    = (const float*)d_in[0];   // [N, 128]
    const float* e_feat = (const float*)d_in[1];   // [E, 32]
    const float* w      = (const float*)d_in[2];   // [1, 128]
    const int*   src    = (const int*)d_in[3];     // [E]
    const int*   dst    = (const int*)d_in[4];     // [E]
    float* out = (float*)d_out;                    // [N, 160]

    const int E = in_sizes[3];
    const int N = out_size / D_OUT;

    // ws layout: cursor[N] | ovf_cnt[1] | pad[1] | bucket[N*CAP] int2 | ovf[E]
    size_t ints_head = (size_t)N + 2;
    size_t need = ints_head * 4 + (size_t)N * CAP * 8 + (size_t)E * 4;

    if (ws_size >= need) {
        int*  cursor  = (int*)d_ws;
        int*  ovf_cnt = cursor + N;
        int2* bucket  = (int2*)(cursor + ints_head);
        int*  ovf     = (int*)(bucket + (size_t)N * CAP);

        hipMemsetAsync(cursor, 0, ints_head * sizeof(int), stream);
        place_bucket_kernel<<<(E + 255) / 256, 256, 0, stream>>>(
            src, dst, cursor, bucket, ovf, ovf_cnt, E);
        gather_bucket_kernel<<<((size_t)N * 32 + 255) / 256, 256, 0, stream>>>(
            emb, e_feat, w, cursor, bucket, out, N);
        ovf_scatter_kernel<<<256, 256, 0, stream>>>(
            emb, e_feat, w, src, dst, ovf, ovf_cnt, out);
    } else {
        hipMemsetAsync(d_out, 0, (size_t)out_size * sizeof(float), stream);
        int items_ft = E * 32, items_e = E * 8;
        scatter_ft_kernel<<<(items_ft + 255) / 256, 256, 0, stream>>>(emb, w, src, dst, out, items_ft);
        scatter_e_kernel<<<(items_e + 255) / 256, 256, 0, stream>>>(e_feat, dst, out, items_e);
    }
}